// Round 1
// baseline (284.856 us; speedup 1.0000x reference)
//
#include <hip/hip_runtime.h>
#include <cstdint>

typedef short bf16x8 __attribute__((ext_vector_type(8)));
typedef float f32x4 __attribute__((ext_vector_type(4)));

#define MFMA16(a, b, c) __builtin_amdgcn_mfma_f32_16x16x32_bf16((a), (b), (c), 0, 0, 0)

__device__ __forceinline__ unsigned short f2b(float f) {
  union { float f; unsigned int u; } x; x.f = f;
  unsigned int r = x.u + 0x7fffu + ((x.u >> 16) & 1u);
  return (unsigned short)(r >> 16);
}

// fast pack two fp32 -> packed bf16x2 (round half-up; fine for probs in [1,16])
__device__ __forceinline__ unsigned int pack2(float lo, float hi) {
  union { float f; unsigned int u; } a, b;
  a.f = lo; b.f = hi;
  return ((a.u + 0x8000u) >> 16) | ((b.u + 0x8000u) & 0xffff0000u);
}

#define NB 2
#define NS 2048
#define ND 768
#define NH 12
#define DHD 64
#define MTOK 4096  // NB*NS

// ws element offsets (ushort/bf16 elements)
#define OFF_XB 0
#define OFF_WB 3145728   // 5 x 589824 converted weights
#define OFF_QK 6094848   // 4 x 3145728 : Qr,Qi,Kr,Ki  [4096][768]
#define OFF_VT 18677760  // Vt [2][12][64][2048]

__global__ void cvt_kernel(const float* __restrict__ src,
                           unsigned short* __restrict__ dst, int n4, float scale) {
  int i = blockIdx.x * blockDim.x + threadIdx.x;
  if (i >= n4) return;
  float4 v = ((const float4*)src)[i];
  ushort4 o;
  o.x = f2b(v.x * scale); o.y = f2b(v.y * scale);
  o.z = f2b(v.z * scale); o.w = f2b(v.w * scale);
  ((ushort4*)dst)[i] = o;
}

// out = X @ W^T for 5 weights (z). z<4 -> row-major bf16 [4096][768];
// z==4 -> V transposed per head: Vt[b][h][dh][s].
// T14: next K-tile prefetched into registers during compute so the
// global-load latency is hidden under the 32-MFMA inner loop.
__global__ __launch_bounds__(256, 3) void proj_kernel(
    const unsigned short* __restrict__ Xb, const unsigned short* __restrict__ Wb,
    unsigned short* __restrict__ QK, unsigned short* __restrict__ Vt) {
  __shared__ __align__(16) unsigned short Xs[128 * 72];
  __shared__ __align__(16) unsigned short Ws[128 * 72];
  const int z = blockIdx.z;
  const int m0 = blockIdx.y * 128;
  const int n0 = blockIdx.x * 128;
  const unsigned short* Wz = Wb + z * 589824;
  const int tid = threadIdx.x;
  const int lane = tid & 63;
  const int w = tid >> 6;
  const int wm = (w >> 1) * 64;
  const int wn = (w & 1) * 64;
  const int col = lane & 15, quad = lane >> 4;

  f32x4 acc[4][4] = {};

  // staging geometry (constant per thread)
  const int r_s = tid >> 3;
  const int c8_s = (tid & 7) * 8;

  // prologue: load K-tile 0 into registers
  uint4 xr[4], wr[4];
#pragma unroll
  for (int i = 0; i < 4; i++) {
    int r = r_s + i * 32;
    xr[i] = *(const uint4*)(Xb + (m0 + r) * ND + c8_s);
    wr[i] = *(const uint4*)(Wz + (n0 + r) * ND + c8_s);
  }

  for (int k0 = 0; k0 < ND; k0 += 64) {
    __syncthreads();
#pragma unroll
    for (int i = 0; i < 4; i++) {
      int r = r_s + i * 32;
      *(uint4*)(Xs + r * 72 + c8_s) = xr[i];
      *(uint4*)(Ws + r * 72 + c8_s) = wr[i];
    }
    __syncthreads();
    // prefetch next K-tile (latency hidden under the MFMAs below)
    if (k0 + 64 < ND) {
#pragma unroll
      for (int i = 0; i < 4; i++) {
        int r = r_s + i * 32;
        xr[i] = *(const uint4*)(Xb + (m0 + r) * ND + k0 + 64 + c8_s);
        wr[i] = *(const uint4*)(Wz + (n0 + r) * ND + k0 + 64 + c8_s);
      }
    }
#pragma unroll
    for (int ks = 0; ks < 2; ks++) {
      bf16x8 af[4], bw[4];
#pragma unroll
      for (int t = 0; t < 4; t++) {
        af[t] = *(const bf16x8*)(Xs + (wm + t * 16 + col) * 72 + ks * 32 + quad * 8);
        bw[t] = *(const bf16x8*)(Ws + (wn + t * 16 + col) * 72 + ks * 32 + quad * 8);
      }
#pragma unroll
      for (int mt = 0; mt < 4; mt++)
#pragma unroll
        for (int nt = 0; nt < 4; nt++)
          acc[mt][nt] = MFMA16(af[mt], bw[nt], acc[mt][nt]);
    }
  }

  if (z < 4) {
    unsigned short* out = QK + z * (MTOK * ND);
#pragma unroll
    for (int mt = 0; mt < 4; mt++) {
      int row0 = m0 + wm + mt * 16 + quad * 4;
#pragma unroll
      for (int nt = 0; nt < 4; nt++) {
        int c = n0 + wn + nt * 16 + col;
#pragma unroll
        for (int r = 0; r < 4; r++) out[(row0 + r) * ND + c] = f2b(acc[mt][nt][r]);
      }
    }
  } else {
#pragma unroll
    for (int mt = 0; mt < 4; mt++) {
      int tok = m0 + wm + mt * 16 + quad * 4;
      int b = tok >> 11, s = tok & 2047;
#pragma unroll
      for (int nt = 0; nt < 4; nt++) {
        int c = n0 + wn + nt * 16 + col;
        int h = c >> 6, dh = c & 63;
        ushort4 pk;
        pk.x = f2b(acc[mt][nt][0]);
        pk.y = f2b(acc[mt][nt][1]);
        pk.z = f2b(acc[mt][nt][2]);
        pk.w = f2b(acc[mt][nt][3]);
        *(ushort4*)(Vt + (((b * NH + h) * DHD + dh) * NS + s)) = pk;
      }
    }
  }
}

// Flash attention, scores transposed (S^T = K Q^T), complex magnitude variant.
// No online max (scores bounded; exp2 domain folded into Q scale).
// LDS XOR-swizzled at 16B granularity: phys block = j ^ (row & 7), stride 64 ushorts.
// T14: K/V tile kt+1 prefetched into registers during the compute phase of
// tile kt so the global-load latency (L2 ~200cy / HBM ~900cy) leaves the
// critical path; vmcnt(0) lands before next iteration's ds_write only.
__global__ __launch_bounds__(256) void attn_kernel(
    const unsigned short* __restrict__ QK, const unsigned short* __restrict__ Vt,
    float* __restrict__ outp) {
  __shared__ __align__(16) unsigned short Krs[4096];
  __shared__ __align__(16) unsigned short Kis[4096];
  __shared__ __align__(16) unsigned short Vts[4096];
  __shared__ __align__(16) unsigned short Ps[4096];

  const int qt = blockIdx.x;
  const int h = blockIdx.y;
  const int b = blockIdx.z;
  const int tid = threadIdx.x, lane = tid & 63, w = tid >> 6;
  const int col = lane & 15, quad = lane >> 4;
  const int c7 = col & 7;
  const int jb = quad ^ c7;
  const int f0 = jb * 8, f1 = (jb ^ 4) * 8;  // swizzled fragment offsets (ushorts)

  const unsigned short* Qr = QK;
  const unsigned short* Qi = QK + MTOK * ND;
  const unsigned short* Krp = QK + 2 * MTOK * ND;
  const unsigned short* Kip = QK + 3 * MTOK * ND;

  const int q_tok = b * NS + qt * 64 + w * 16 + col;
  const int qoff = q_tok * ND + h * DHD;

  // Q as B-fragments: B[k=d][n=q], lane holds 8 consecutive d at its q.
  bf16x8 qrf[2], qif[2], qrn[2];
#pragma unroll
  for (int kk = 0; kk < 2; kk++) {
    qrf[kk] = *(const bf16x8*)(Qr + qoff + kk * 32 + quad * 8);
    qif[kk] = *(const bf16x8*)(Qi + qoff + kk * 32 + quad * 8);
    qrn[kk] = qrf[kk] ^ (short)0x8000;  // -Qr (bf16 sign flip)
  }

  // staging: thread -> (row, block); i=1 handles row+32 (same row&7 -> same xor)
  const int r0 = tid >> 3;
  const int j0 = tid & 7;
  const int dst0 = r0 * 64 + ((j0 ^ (r0 & 7)) * 8);

  const unsigned short* pKr = Krp + (b * NS + r0) * ND + h * DHD + j0 * 8;
  const unsigned short* pKi = Kip + (b * NS + r0) * ND + h * DHD + j0 * 8;
  const unsigned short* pV = Vt + (b * NH + h) * (DHD * NS) + r0 * NS + j0 * 8;

  unsigned short* PsW = Ps + w * 1024;

  f32x4 o[4] = {};  // O^T tiles: rows d = dt*16+quad*4+r, col q
  float lrow = 0.f;

  // prologue: load tile 0 into registers
  uint4 kr_a = *(const uint4*)pKr;
  uint4 kr_b = *(const uint4*)(pKr + 32 * ND);
  uint4 ki_a = *(const uint4*)pKi;
  uint4 ki_b = *(const uint4*)(pKi + 32 * ND);
  uint4 v_a = *(const uint4*)pV;
  uint4 v_b = *(const uint4*)(pV + 32 * NS);
  pKr += 64 * ND;
  pKi += 64 * ND;
  pV += 64;

  for (int kt = 0; kt < 32; kt++) {
    __syncthreads();
    *(uint4*)(Krs + dst0) = kr_a;
    *(uint4*)(Krs + dst0 + 2048) = kr_b;
    *(uint4*)(Kis + dst0) = ki_a;
    *(uint4*)(Kis + dst0 + 2048) = ki_b;
    *(uint4*)(Vts + dst0) = v_a;
    *(uint4*)(Vts + dst0 + 2048) = v_b;
    __syncthreads();

    // prefetch tile kt+1 into registers; consumed by next iteration's ds_write
    if (kt < 31) {
      kr_a = *(const uint4*)pKr;
      kr_b = *(const uint4*)(pKr + 32 * ND);
      ki_a = *(const uint4*)pKi;
      ki_b = *(const uint4*)(pKi + 32 * ND);
      v_a = *(const uint4*)pV;
      v_b = *(const uint4*)(pV + 32 * NS);
      pKr += 64 * ND;
      pKi += 64 * ND;
      pV += 64;
    }

#pragma unroll
    for (int mt = 0; mt < 4; mt++) {
      f32x4 sr = {}, si = {};
      const int rowb = (mt * 16 + col) * 64;
      bf16x8 kr0 = *(const bf16x8*)(Krs + rowb + f0);
      bf16x8 ki0 = *(const bf16x8*)(Kis + rowb + f0);
      bf16x8 kr1 = *(const bf16x8*)(Krs + rowb + f1);
      bf16x8 ki1 = *(const bf16x8*)(Kis + rowb + f1);
      sr = MFMA16(kr0, qrf[0], sr);
      sr = MFMA16(ki0, qif[0], sr);
      si = MFMA16(kr0, qif[0], si);
      si = MFMA16(ki0, qrn[0], si);
      sr = MFMA16(kr1, qrf[1], sr);
      sr = MFMA16(ki1, qif[1], sr);
      si = MFMA16(kr1, qif[1], si);
      si = MFMA16(ki1, qrn[1], si);

      float e0, e1, e2, e3;
      {
        float m0f = __builtin_amdgcn_sqrtf(sr[0] * sr[0] + si[0] * si[0]);
        float m1f = __builtin_amdgcn_sqrtf(sr[1] * sr[1] + si[1] * si[1]);
        float m2f = __builtin_amdgcn_sqrtf(sr[2] * sr[2] + si[2] * si[2]);
        float m3f = __builtin_amdgcn_sqrtf(sr[3] * sr[3] + si[3] * si[3]);
        e0 = __builtin_amdgcn_exp2f(m0f);
        e1 = __builtin_amdgcn_exp2f(m1f);
        e2 = __builtin_amdgcn_exp2f(m2f);
        e3 = __builtin_amdgcn_exp2f(m3f);
      }
      lrow += (e0 + e1) + (e2 + e3);
      uint2 pk;
      pk.x = pack2(e0, e1);
      pk.y = pack2(e2, e3);
      *(uint2*)(PsW + col * 64 + (((mt * 2 + (quad >> 1)) ^ c7) * 8) + (quad & 1) * 4) = pk;
    }
    asm volatile("s_waitcnt lgkmcnt(0)" ::: "memory");

    // O^T += V^T · P^T
    bf16x8 pb0 = *(const bf16x8*)(PsW + col * 64 + f0);
    bf16x8 pb1 = *(const bf16x8*)(PsW + col * 64 + f1);
#pragma unroll
    for (int dt = 0; dt < 4; dt++) {
      const int rowv = (dt * 16 + col) * 64;
      bf16x8 va0 = *(const bf16x8*)(Vts + rowv + f0);
      bf16x8 va1 = *(const bf16x8*)(Vts + rowv + f1);
      o[dt] = MFMA16(va0, pb0, o[dt]);
      o[dt] = MFMA16(va1, pb1, o[dt]);
    }
  }

  lrow += __shfl_xor(lrow, 16);
  lrow += __shfl_xor(lrow, 32);
  float inv_l = 1.0f / lrow;
  float* op = outp + (size_t)q_tok * ND + h * DHD;
#pragma unroll
  for (int dt = 0; dt < 4; dt++) {
    float4 v;
    v.x = o[dt][0] * inv_l;
    v.y = o[dt][1] * inv_l;
    v.z = o[dt][2] * inv_l;
    v.w = o[dt][3] * inv_l;
    *(float4*)(op + dt * 16 + quad * 4) = v;
  }
}

extern "C" void kernel_launch(void* const* d_in, const int* in_sizes, int n_in,
                              void* d_out, int out_size, void* d_ws, size_t ws_size,
                              hipStream_t stream) {
  const float* X = (const float*)d_in[0];
  unsigned short* ws = (unsigned short*)d_ws;
  unsigned short* Xb = ws + OFF_XB;
  unsigned short* Wb = ws + OFF_WB;
  unsigned short* QK = ws + OFF_QK;
  unsigned short* Vt = ws + OFF_VT;

  // scale = 1/sqrt(Dh) * log2(e), folded into Wq so scores come out in exp2 domain
  const float QSCALE = 0.125f * 1.44269504088896f;

  cvt_kernel<<<3072, 256, 0, stream>>>(X, Xb, 786432, 1.0f);
  for (int z = 0; z < 5; z++) {
    float sc = (z == 0 || z == 1) ? QSCALE : 1.0f;  // Wqr, Wqi
    cvt_kernel<<<576, 256, 0, stream>>>((const float*)d_in[1 + z],
                                        Wb + z * 589824, 147456, sc);
  }

  proj_kernel<<<dim3(6, 32, 5), 256, 0, stream>>>(Xb, Wb, QK, Vt);
  attn_kernel<<<dim3(32, 12, 2), 256, 0, stream>>>(QK, Vt, (float*)d_out);
}

// Round 2
// 227.032 us; speedup vs baseline: 1.2547x; 1.2547x over previous
//
#include <hip/hip_runtime.h>
#include <cstdint>

typedef short bf16x8 __attribute__((ext_vector_type(8)));
typedef float f32x4 __attribute__((ext_vector_type(4)));

#define MFMA16(a, b, c) __builtin_amdgcn_mfma_f32_16x16x32_bf16((a), (b), (c), 0, 0, 0)

__device__ __forceinline__ unsigned short f2b(float f) {
  union { float f; unsigned int u; } x; x.f = f;
  unsigned int r = x.u + 0x7fffu + ((x.u >> 16) & 1u);
  return (unsigned short)(r >> 16);
}

// fast pack two fp32 -> packed bf16x2 (round half-up; fine for probs in [1,16])
__device__ __forceinline__ unsigned int pack2(float lo, float hi) {
  union { float f; unsigned int u; } a, b;
  a.f = lo; b.f = hi;
  return ((a.u + 0x8000u) >> 16) | ((b.u + 0x8000u) & 0xffff0000u);
}

#define NB 2
#define NS 2048
#define ND 768
#define NH 12
#define DHD 64
#define MTOK 4096  // NB*NS

// ws element offsets (ushort/bf16 elements)
#define OFF_XB 0
#define OFF_WB 3145728   // 5 x 589824 converted weights
#define OFF_QK 6094848   // 4 x 3145728 : Qr,Qi,Kr,Ki  [4096][768]
#define OFF_VT 18677760  // Vt [2][12][64][2048]

__global__ void cvt_kernel(const float* __restrict__ src,
                           unsigned short* __restrict__ dst, int n4, float scale) {
  int i = blockIdx.x * blockDim.x + threadIdx.x;
  if (i >= n4) return;
  float4 v = ((const float4*)src)[i];
  ushort4 o;
  o.x = f2b(v.x * scale); o.y = f2b(v.y * scale);
  o.z = f2b(v.z * scale); o.w = f2b(v.w * scale);
  ((ushort4*)dst)[i] = o;
}

// out = X @ W^T for 5 weights (z). z<4 -> row-major bf16 [4096][768];
// z==4 -> V transposed per head: Vt[b][h][dh][s].
// Grid (n, z, m0) + XCD-chunked swizzle: 30 consecutive swizzled blocks
// (5 weights x 6 n-blocks) share one X panel inside one XCD's L2.
// Epilogue stages the 128x128 output tile in LDS (stride 136 to dodge bank
// conflicts) and streams it out as full-line coalesced uint4 rows -> kills
// the 9x write amplification the scalar/strided stores caused.
__global__ __launch_bounds__(256) void proj_kernel(
    const unsigned short* __restrict__ Xb, const unsigned short* __restrict__ Wb,
    unsigned short* __restrict__ QK, unsigned short* __restrict__ Vt) {
  __shared__ __align__(16) unsigned short S[18432];  // 36864 B
  unsigned short* Xs = S;            // [128][72]
  unsigned short* Ws = S + 9216;     // [128][72]

  // swizzled block decode: lin -> s so each XCD gets 120 consecutive s
  const int lin = blockIdx.x + 6 * (blockIdx.y + 5 * blockIdx.z);
  const int sb = (lin & 7) * 120 + (lin >> 3);
  const int n0 = (sb % 6) * 128;
  const int rem = sb / 6;
  const int z = rem % 5;
  const int m0 = (rem / 5) * 128;

  const unsigned short* Wz = Wb + z * 589824;
  const int tid = threadIdx.x;
  const int lane = tid & 63;
  const int w = tid >> 6;
  const int wm = (w >> 1) * 64;
  const int wn = (w & 1) * 64;
  const int col = lane & 15, quad = lane >> 4;

  f32x4 acc[4][4] = {};

  for (int k0 = 0; k0 < ND; k0 += 64) {
    __syncthreads();
#pragma unroll
    for (int i = 0; i < 4; i++) {
      int idx = tid + i * 256;
      int r = idx >> 3, c8 = (idx & 7) * 8;
      *(uint4*)(Xs + r * 72 + c8) = *(const uint4*)(Xb + (m0 + r) * ND + k0 + c8);
      *(uint4*)(Ws + r * 72 + c8) = *(const uint4*)(Wz + (n0 + r) * ND + k0 + c8);
    }
    __syncthreads();
#pragma unroll
    for (int ks = 0; ks < 2; ks++) {
      bf16x8 af[4], bw[4];
#pragma unroll
      for (int t = 0; t < 4; t++) {
        af[t] = *(const bf16x8*)(Xs + (wm + t * 16 + col) * 72 + ks * 32 + quad * 8);
        bw[t] = *(const bf16x8*)(Ws + (wn + t * 16 + col) * 72 + ks * 32 + quad * 8);
      }
#pragma unroll
      for (int mt = 0; mt < 4; mt++)
#pragma unroll
        for (int nt = 0; nt < 4; nt++)
          acc[mt][nt] = MFMA16(af[mt], bw[nt], acc[mt][nt]);
    }
  }

  // ---- epilogue: LDS-staged coalesced writeout ----
  __syncthreads();  // done reading Xs/Ws; reuse S as output tile T[128][136]
  unsigned short* T = S;

  if (z < 4) {
#pragma unroll
    for (int mt = 0; mt < 4; mt++) {
      int rl = wm + mt * 16 + quad * 4;
#pragma unroll
      for (int nt = 0; nt < 4; nt++) {
        int cl = wn + nt * 16 + col;
#pragma unroll
        for (int r = 0; r < 4; r++) T[(rl + r) * 136 + cl] = f2b(acc[mt][nt][r]);
      }
    }
    __syncthreads();
    unsigned short* out = QK + z * (MTOK * ND);
    const int rr = tid >> 4;
    const int cc = (tid & 15) * 8;
#pragma unroll
    for (int p = 0; p < 8; p++) {
      int row = p * 16 + rr;
      uint4 v = *(const uint4*)(T + row * 136 + cc);
      *(uint4*)(out + (m0 + row) * ND + n0 + cc) = v;
    }
  } else {
    // transpose in LDS: T[dh_local][s_local], so global write is contiguous in s
#pragma unroll
    for (int mt = 0; mt < 4; mt++) {
      int rl = wm + mt * 16 + quad * 4;  // token index (s_local), multiple of 4
#pragma unroll
      for (int nt = 0; nt < 4; nt++) {
        int cl = wn + nt * 16 + col;  // dh_local
        ushort4 pk;
        pk.x = f2b(acc[mt][nt][0]);
        pk.y = f2b(acc[mt][nt][1]);
        pk.z = f2b(acc[mt][nt][2]);
        pk.w = f2b(acc[mt][nt][3]);
        *(ushort4*)(T + cl * 136 + rl) = pk;
      }
    }
    __syncthreads();
    const int rr = tid >> 4;
    const int cc = (tid & 15) * 8;
    const int b = m0 >> 11;
    const int s_base = m0 & 2047;
#pragma unroll
    for (int p = 0; p < 8; p++) {
      int dhl = p * 16 + rr;
      int c = n0 + dhl;
      int h = c >> 6, dh = c & 63;
      uint4 v = *(const uint4*)(T + dhl * 136 + cc);
      *(uint4*)(Vt + (((b * NH + h) * DHD + dh) * NS + s_base + cc)) = v;
    }
  }
}

// Flash attention, scores transposed (S^T = K Q^T), complex magnitude variant.
// No online max (scores bounded; exp2 domain folded into Q scale).
// LDS XOR-swizzled at 16B granularity: phys block = j ^ (row & 7), stride 64 ushorts.
// XCD-chunked swizzle: 96 consecutive swizzled blocks = 3 full (b,h) groups
// per XCD -> K/V panels (768 KB each) stay resident in that XCD's L2.
__global__ __launch_bounds__(256) void attn_kernel(
    const unsigned short* __restrict__ QK, const unsigned short* __restrict__ Vt,
    float* __restrict__ outp) {
  __shared__ __align__(16) unsigned short Krs[4096];
  __shared__ __align__(16) unsigned short Kis[4096];
  __shared__ __align__(16) unsigned short Vts[4096];
  __shared__ __align__(16) unsigned short Ps[4096];

  const int lin = blockIdx.x + 32 * (blockIdx.y + 12 * blockIdx.z);
  const int sb = (lin & 7) * 96 + (lin >> 3);
  const int qt = sb & 31;
  const int h = (sb >> 5) % 12;
  const int b = sb / 384;
  const int tid = threadIdx.x, lane = tid & 63, w = tid >> 6;
  const int col = lane & 15, quad = lane >> 4;
  const int c7 = col & 7;
  const int jb = quad ^ c7;
  const int f0 = jb * 8, f1 = (jb ^ 4) * 8;  // swizzled fragment offsets (ushorts)

  const unsigned short* Qr = QK;
  const unsigned short* Qi = QK + MTOK * ND;
  const unsigned short* Krp = QK + 2 * MTOK * ND;
  const unsigned short* Kip = QK + 3 * MTOK * ND;

  const int q_tok = b * NS + qt * 64 + w * 16 + col;
  const int qoff = q_tok * ND + h * DHD;

  // Q as B-fragments: B[k=d][n=q], lane holds 8 consecutive d at its q.
  bf16x8 qrf[2], qif[2], qrn[2];
#pragma unroll
  for (int kk = 0; kk < 2; kk++) {
    qrf[kk] = *(const bf16x8*)(Qr + qoff + kk * 32 + quad * 8);
    qif[kk] = *(const bf16x8*)(Qi + qoff + kk * 32 + quad * 8);
    qrn[kk] = qrf[kk] ^ (short)0x8000;  // -Qr (bf16 sign flip)
  }

  // staging: thread -> (row, block); i=1 handles row+32 (same row&7 -> same xor)
  const int r0 = tid >> 3;
  const int j0 = tid & 7;
  const int dst0 = r0 * 64 + ((j0 ^ (r0 & 7)) * 8);

  const unsigned short* pKr = Krp + (b * NS + r0) * ND + h * DHD + j0 * 8;
  const unsigned short* pKi = Kip + (b * NS + r0) * ND + h * DHD + j0 * 8;
  const unsigned short* pV = Vt + (b * NH + h) * (DHD * NS) + r0 * NS + j0 * 8;

  unsigned short* PsW = Ps + w * 1024;

  f32x4 o[4] = {};  // O^T tiles: rows d = dt*16+quad*4+r, col q
  float lrow = 0.f;

  for (int kt = 0; kt < 32; kt++) {
    __syncthreads();
    *(uint4*)(Krs + dst0) = *(const uint4*)pKr;
    *(uint4*)(Krs + dst0 + 2048) = *(const uint4*)(pKr + 32 * ND);
    *(uint4*)(Kis + dst0) = *(const uint4*)pKi;
    *(uint4*)(Kis + dst0 + 2048) = *(const uint4*)(pKi + 32 * ND);
    *(uint4*)(Vts + dst0) = *(const uint4*)pV;
    *(uint4*)(Vts + dst0 + 2048) = *(const uint4*)(pV + 32 * NS);
    pKr += 64 * ND;
    pKi += 64 * ND;
    pV += 64;
    __syncthreads();

#pragma unroll
    for (int mt = 0; mt < 4; mt++) {
      f32x4 sr = {}, si = {};
      const int rowb = (mt * 16 + col) * 64;
      bf16x8 kr0 = *(const bf16x8*)(Krs + rowb + f0);
      bf16x8 ki0 = *(const bf16x8*)(Kis + rowb + f0);
      bf16x8 kr1 = *(const bf16x8*)(Krs + rowb + f1);
      bf16x8 ki1 = *(const bf16x8*)(Kis + rowb + f1);
      sr = MFMA16(kr0, qrf[0], sr);
      sr = MFMA16(ki0, qif[0], sr);
      si = MFMA16(kr0, qif[0], si);
      si = MFMA16(ki0, qrn[0], si);
      sr = MFMA16(kr1, qrf[1], sr);
      sr = MFMA16(ki1, qif[1], sr);
      si = MFMA16(kr1, qif[1], si);
      si = MFMA16(ki1, qrn[1], si);

      float e0, e1, e2, e3;
      {
        float m0f = __builtin_amdgcn_sqrtf(sr[0] * sr[0] + si[0] * si[0]);
        float m1f = __builtin_amdgcn_sqrtf(sr[1] * sr[1] + si[1] * si[1]);
        float m2f = __builtin_amdgcn_sqrtf(sr[2] * sr[2] + si[2] * si[2]);
        float m3f = __builtin_amdgcn_sqrtf(sr[3] * sr[3] + si[3] * si[3]);
        e0 = __builtin_amdgcn_exp2f(m0f);
        e1 = __builtin_amdgcn_exp2f(m1f);
        e2 = __builtin_amdgcn_exp2f(m2f);
        e3 = __builtin_amdgcn_exp2f(m3f);
      }
      lrow += (e0 + e1) + (e2 + e3);
      uint2 pk;
      pk.x = pack2(e0, e1);
      pk.y = pack2(e2, e3);
      *(uint2*)(PsW + col * 64 + (((mt * 2 + (quad >> 1)) ^ c7) * 8) + (quad & 1) * 4) = pk;
    }
    asm volatile("s_waitcnt lgkmcnt(0)" ::: "memory");

    // O^T += V^T · P^T
    bf16x8 pb0 = *(const bf16x8*)(PsW + col * 64 + f0);
    bf16x8 pb1 = *(const bf16x8*)(PsW + col * 64 + f1);
#pragma unroll
    for (int dt = 0; dt < 4; dt++) {
      const int rowv = (dt * 16 + col) * 64;
      bf16x8 va0 = *(const bf16x8*)(Vts + rowv + f0);
      bf16x8 va1 = *(const bf16x8*)(Vts + rowv + f1);
      o[dt] = MFMA16(va0, pb0, o[dt]);
      o[dt] = MFMA16(va1, pb1, o[dt]);
    }
  }

  lrow += __shfl_xor(lrow, 16);
  lrow += __shfl_xor(lrow, 32);
  float inv_l = 1.0f / lrow;
  float* op = outp + (size_t)q_tok * ND + h * DHD;
#pragma unroll
  for (int dt = 0; dt < 4; dt++) {
    float4 v;
    v.x = o[dt][0] * inv_l;
    v.y = o[dt][1] * inv_l;
    v.z = o[dt][2] * inv_l;
    v.w = o[dt][3] * inv_l;
    *(float4*)(op + dt * 16 + quad * 4) = v;
  }
}

extern "C" void kernel_launch(void* const* d_in, const int* in_sizes, int n_in,
                              void* d_out, int out_size, void* d_ws, size_t ws_size,
                              hipStream_t stream) {
  const float* X = (const float*)d_in[0];
  unsigned short* ws = (unsigned short*)d_ws;
  unsigned short* Xb = ws + OFF_XB;
  unsigned short* Wb = ws + OFF_WB;
  unsigned short* QK = ws + OFF_QK;
  unsigned short* Vt = ws + OFF_VT;

  // scale = 1/sqrt(Dh) * log2(e), folded into Wq so scores come out in exp2 domain
  const float QSCALE = 0.125f * 1.44269504088896f;

  cvt_kernel<<<3072, 256, 0, stream>>>(X, Xb, 786432, 1.0f);
  for (int z = 0; z < 5; z++) {
    float sc = (z == 0 || z == 1) ? QSCALE : 1.0f;  // Wqr, Wqi
    cvt_kernel<<<576, 256, 0, stream>>>((const float*)d_in[1 + z],
                                        Wb + z * 589824, 147456, sc);
  }

  proj_kernel<<<dim3(6, 5, 32), 256, 0, stream>>>(Xb, Wb, QK, Vt);
  attn_kernel<<<dim3(32, 12, 2), 256, 0, stream>>>(QK, Vt, (float*)d_out);
}

// Round 3
// 193.304 us; speedup vs baseline: 1.4736x; 1.1745x over previous
//
#include <hip/hip_runtime.h>
#include <cstdint>

typedef short bf16x8 __attribute__((ext_vector_type(8)));
typedef float f32x4 __attribute__((ext_vector_type(4)));

#define MFMA16(a, b, c) __builtin_amdgcn_mfma_f32_16x16x32_bf16((a), (b), (c), 0, 0, 0)

// async global->LDS DMA, 16B per lane. LDS dest is wave-uniform base + lane*16.
__device__ __forceinline__ void gl16(const unsigned short* g, unsigned short* l) {
  __builtin_amdgcn_global_load_lds(
      (const __attribute__((address_space(1))) unsigned int*)g,
      (__attribute__((address_space(3))) unsigned int*)l, 16, 0, 0);
}

__device__ __forceinline__ unsigned short f2b(float f) {
  union { float f; unsigned int u; } x; x.f = f;
  unsigned int r = x.u + 0x7fffu + ((x.u >> 16) & 1u);
  return (unsigned short)(r >> 16);
}

// fast pack two fp32 -> packed bf16x2 (round half-up; fine for probs in [1,16])
__device__ __forceinline__ unsigned int pack2(float lo, float hi) {
  union { float f; unsigned int u; } a, b;
  a.f = lo; b.f = hi;
  return ((a.u + 0x8000u) >> 16) | ((b.u + 0x8000u) & 0xffff0000u);
}

#define NB 2
#define NS 2048
#define ND 768
#define NH 12
#define DHD 64
#define MTOK 4096  // NB*NS

// ws element offsets (ushort/bf16 elements)
#define OFF_XB 0
#define OFF_WB 3145728   // 5 x 589824 converted weights
#define OFF_QK 6094848   // 4 x 3145728 : Qr,Qi,Kr,Ki  [4096][768]
#define OFF_VT 18677760  // Vt [2][12][64][2048]

__global__ void cvt_kernel(const float* __restrict__ src,
                           unsigned short* __restrict__ dst, int n4, float scale) {
  int i = blockIdx.x * blockDim.x + threadIdx.x;
  if (i >= n4) return;
  float4 v = ((const float4*)src)[i];
  ushort4 o;
  o.x = f2b(v.x * scale); o.y = f2b(v.y * scale);
  o.z = f2b(v.z * scale); o.w = f2b(v.w * scale);
  ((ushort4*)dst)[i] = o;
}

// all 5 weight matrices in one launch (saves 4 graph-node overheads)
__global__ void wcvt_kernel(const float* __restrict__ s0, const float* __restrict__ s1,
                            const float* __restrict__ s2, const float* __restrict__ s3,
                            const float* __restrict__ s4, unsigned short* __restrict__ dst,
                            float qs) {
  const int bz = blockIdx.x / 576;           // 576 blocks per weight (147456/256)
  const int i = (blockIdx.x % 576) * 256 + threadIdx.x;
  const float* src = bz == 0 ? s0 : bz == 1 ? s1 : bz == 2 ? s2 : bz == 3 ? s3 : s4;
  const float scale = bz < 2 ? qs : 1.0f;    // Wqr, Wqi carry the exp2-domain scale
  float4 v = ((const float4*)src)[i];
  ushort4 o;
  o.x = f2b(v.x * scale); o.y = f2b(v.y * scale);
  o.z = f2b(v.z * scale); o.w = f2b(v.w * scale);
  ((ushort4*)(dst + bz * 589824))[i] = o;
}

// out = X @ W^T for 5 weights (z). z<4 -> row-major bf16 [4096][768];
// z==4 -> V transposed per head: Vt[b][h][dh][s].
// m97 structure: linear LDS [128][64] + global_load_lds(16B) staging, XOR
// swizzle applied to the GLOBAL source chunk and to the ds_read offset
// (rule #21: both-sides-or-neither). LDS[r][c] = G[r][c ^ (r&7)].
// Grid (n, z, m0) + XCD-chunked swizzle: 30 consecutive swizzled blocks
// share one X panel inside one XCD's L2. Coalesced LDS-staged epilogue.
__global__ __launch_bounds__(256) void proj_kernel(
    const unsigned short* __restrict__ Xb, const unsigned short* __restrict__ Wb,
    unsigned short* __restrict__ QK, unsigned short* __restrict__ Vt) {
  __shared__ __align__(16) unsigned short S[17408];  // staging 2x8192; epilogue 128x136
  unsigned short* Xs = S;            // [128][64] linear
  unsigned short* Ws = S + 8192;     // [128][64] linear

  // swizzled block decode: lin -> sb so each XCD gets 120 consecutive sb
  const int lin = blockIdx.x + 6 * (blockIdx.y + 5 * blockIdx.z);
  const int sb = (lin & 7) * 120 + (lin >> 3);
  const int n0 = (sb % 6) * 128;
  const int rem = sb / 6;
  const int z = rem % 5;
  const int m0 = (rem / 5) * 128;

  const unsigned short* Wz = Wb + z * 589824;
  const int tid = threadIdx.x;
  const int lane = tid & 63;
  const int w = tid >> 6;
  const int wm = (w >> 1) * 64;
  const int wn = (w & 1) * 64;
  const int col = lane & 15, quad = lane >> 4;
  const int c7 = col & 7;

  // staging geometry: wave w covers rows [w*32, w*32+32) in 4 instrs of 8 rows
  const int lr = lane >> 3;                    // row within 8-row group
  const int lc = (lane & 7) ^ (lr & 7);        // pre-swizzled source chunk
  const unsigned short* gX = Xb + (m0 + w * 32 + lr) * ND + lc * 8;
  const unsigned short* gW = Wz + (n0 + w * 32 + lr) * ND + lc * 8;
  unsigned short* lX = Xs + (w * 32) * 64;     // wave-uniform LDS base
  unsigned short* lW = Ws + (w * 32) * 64;

  f32x4 acc[4][4] = {};

  for (int k0 = 0; k0 < ND; k0 += 64) {
    __syncthreads();
#pragma unroll
    for (int i = 0; i < 4; i++) {
      gl16(gX + i * (8 * ND) + k0, lX + i * (8 * 64));
      gl16(gW + i * (8 * ND) + k0, lW + i * (8 * 64));
    }
    __syncthreads();  // drains vmcnt(0): staged data visible
#pragma unroll
    for (int ks = 0; ks < 2; ks++) {
      bf16x8 af[4], bw[4];
#pragma unroll
      for (int t = 0; t < 4; t++) {
        const int fo = (((ks * 4 + quad) ^ c7) * 8);
        af[t] = *(const bf16x8*)(Xs + (wm + t * 16 + col) * 64 + fo);
        bw[t] = *(const bf16x8*)(Ws + (wn + t * 16 + col) * 64 + fo);
      }
#pragma unroll
      for (int mt = 0; mt < 4; mt++)
#pragma unroll
        for (int nt = 0; nt < 4; nt++)
          acc[mt][nt] = MFMA16(af[mt], bw[nt], acc[mt][nt]);
    }
  }

  // ---- epilogue: LDS-staged coalesced writeout ----
  __syncthreads();  // done reading Xs/Ws; reuse S as output tile T[128][136]
  unsigned short* T = S;

  if (z < 4) {
#pragma unroll
    for (int mt = 0; mt < 4; mt++) {
      int rl = wm + mt * 16 + quad * 4;
#pragma unroll
      for (int nt = 0; nt < 4; nt++) {
        int cl = wn + nt * 16 + col;
#pragma unroll
        for (int r = 0; r < 4; r++) T[(rl + r) * 136 + cl] = f2b(acc[mt][nt][r]);
      }
    }
    __syncthreads();
    unsigned short* out = QK + z * (MTOK * ND);
    const int rr = tid >> 4;
    const int cc = (tid & 15) * 8;
#pragma unroll
    for (int p = 0; p < 8; p++) {
      int row = p * 16 + rr;
      uint4 v = *(const uint4*)(T + row * 136 + cc);
      *(uint4*)(out + (m0 + row) * ND + n0 + cc) = v;
    }
  } else {
    // transpose in LDS: T[dh_local][s_local], so global write is contiguous in s
#pragma unroll
    for (int mt = 0; mt < 4; mt++) {
      int rl = wm + mt * 16 + quad * 4;  // token index (s_local), multiple of 4
#pragma unroll
      for (int nt = 0; nt < 4; nt++) {
        int cl = wn + nt * 16 + col;  // dh_local
        ushort4 pk;
        pk.x = f2b(acc[mt][nt][0]);
        pk.y = f2b(acc[mt][nt][1]);
        pk.z = f2b(acc[mt][nt][2]);
        pk.w = f2b(acc[mt][nt][3]);
        *(ushort4*)(T + cl * 136 + rl) = pk;
      }
    }
    __syncthreads();
    const int rr = tid >> 4;
    const int cc = (tid & 15) * 8;
    const int b = m0 >> 11;
    const int s_base = m0 & 2047;
#pragma unroll
    for (int p = 0; p < 8; p++) {
      int dhl = p * 16 + rr;
      int c = n0 + dhl;
      int h = c >> 6, dh = c & 63;
      uint4 v = *(const uint4*)(T + dhl * 136 + cc);
      *(uint4*)(Vt + (((b * NH + h) * DHD + dh) * NS + s_base + cc)) = v;
    }
  }
}

// Flash attention, scores transposed (S^T = K Q^T), complex magnitude variant.
// No online max (scores bounded; exp2 domain folded into Q scale).
// Staging now via global_load_lds: linear LDS dest, XOR swizzle moved to the
// global source chunk; LDS content identical to the verified reg-staged
// version, so the compute section is byte-for-byte unchanged.
// XCD-chunked swizzle keeps K/V panels resident in one XCD's L2.
__global__ __launch_bounds__(256) void attn_kernel(
    const unsigned short* __restrict__ QK, const unsigned short* __restrict__ Vt,
    float* __restrict__ outp) {
  __shared__ __align__(16) unsigned short Krs[4096];
  __shared__ __align__(16) unsigned short Kis[4096];
  __shared__ __align__(16) unsigned short Vts[4096];
  __shared__ __align__(16) unsigned short Ps[4096];

  const int lin = blockIdx.x + 32 * (blockIdx.y + 12 * blockIdx.z);
  const int sb = (lin & 7) * 96 + (lin >> 3);
  const int qt = sb & 31;
  const int h = (sb >> 5) % 12;
  const int b = sb / 384;
  const int tid = threadIdx.x, lane = tid & 63, w = tid >> 6;
  const int col = lane & 15, quad = lane >> 4;
  const int c7 = col & 7;
  const int jb = quad ^ c7;
  const int f0 = jb * 8, f1 = (jb ^ 4) * 8;  // swizzled fragment offsets (ushorts)

  const unsigned short* Qr = QK;
  const unsigned short* Qi = QK + MTOK * ND;
  const unsigned short* Krp = QK + 2 * MTOK * ND;
  const unsigned short* Kip = QK + 3 * MTOK * ND;

  const int q_tok = b * NS + qt * 64 + w * 16 + col;
  const int qoff = q_tok * ND + h * DHD;

  // Q as B-fragments: B[k=d][n=q], lane holds 8 consecutive d at its q.
  bf16x8 qrf[2], qif[2], qrn[2];
#pragma unroll
  for (int kk = 0; kk < 2; kk++) {
    qrf[kk] = *(const bf16x8*)(Qr + qoff + kk * 32 + quad * 8);
    qif[kk] = *(const bf16x8*)(Qi + qoff + kk * 32 + quad * 8);
    qrn[kk] = qrf[kk] ^ (short)0x8000;  // -Qr (bf16 sign flip)
  }

  // staging: wave w stages rows [w*8, w*8+8) and [32+w*8, ...) of each array.
  // lane -> row w*8 + (lane>>3), source chunk (lane&7) ^ (row&7).
  const int lr = lane >> 3;
  const int lc = (lane & 7) ^ (lr & 7);
  const unsigned short* gKr = Krp + (b * NS + w * 8 + lr) * ND + h * DHD + lc * 8;
  const unsigned short* gKi = Kip + (b * NS + w * 8 + lr) * ND + h * DHD + lc * 8;
  const unsigned short* gV = Vt + (b * NH + h) * (DHD * NS) + (w * 8 + lr) * NS + lc * 8;
  unsigned short* lKr = Krs + (w * 8) * 64;  // wave-uniform LDS bases
  unsigned short* lKi = Kis + (w * 8) * 64;
  unsigned short* lV = Vts + (w * 8) * 64;

  unsigned short* PsW = Ps + w * 1024;

  f32x4 o[4] = {};  // O^T tiles: rows d = dt*16+quad*4+r, col q
  float lrow = 0.f;

  for (int kt = 0; kt < 32; kt++) {
    __syncthreads();
    gl16(gKr, lKr);
    gl16(gKr + 32 * ND, lKr + 2048);
    gl16(gKi, lKi);
    gl16(gKi + 32 * ND, lKi + 2048);
    gl16(gV, lV);
    gl16(gV + 32 * NS, lV + 2048);
    gKr += 64 * ND;
    gKi += 64 * ND;
    gV += 64;
    __syncthreads();  // drains vmcnt(0): staged tile visible

#pragma unroll
    for (int mt = 0; mt < 4; mt++) {
      f32x4 sr = {}, si = {};
      const int rowb = (mt * 16 + col) * 64;
      bf16x8 kr0 = *(const bf16x8*)(Krs + rowb + f0);
      bf16x8 ki0 = *(const bf16x8*)(Kis + rowb + f0);
      bf16x8 kr1 = *(const bf16x8*)(Krs + rowb + f1);
      bf16x8 ki1 = *(const bf16x8*)(Kis + rowb + f1);
      sr = MFMA16(kr0, qrf[0], sr);
      sr = MFMA16(ki0, qif[0], sr);
      si = MFMA16(kr0, qif[0], si);
      si = MFMA16(ki0, qrn[0], si);
      sr = MFMA16(kr1, qrf[1], sr);
      sr = MFMA16(ki1, qif[1], sr);
      si = MFMA16(kr1, qif[1], si);
      si = MFMA16(ki1, qrn[1], si);

      float e0, e1, e2, e3;
      {
        float m0f = __builtin_amdgcn_sqrtf(sr[0] * sr[0] + si[0] * si[0]);
        float m1f = __builtin_amdgcn_sqrtf(sr[1] * sr[1] + si[1] * si[1]);
        float m2f = __builtin_amdgcn_sqrtf(sr[2] * sr[2] + si[2] * si[2]);
        float m3f = __builtin_amdgcn_sqrtf(sr[3] * sr[3] + si[3] * si[3]);
        e0 = __builtin_amdgcn_exp2f(m0f);
        e1 = __builtin_amdgcn_exp2f(m1f);
        e2 = __builtin_amdgcn_exp2f(m2f);
        e3 = __builtin_amdgcn_exp2f(m3f);
      }
      lrow += (e0 + e1) + (e2 + e3);
      uint2 pk;
      pk.x = pack2(e0, e1);
      pk.y = pack2(e2, e3);
      *(uint2*)(PsW + col * 64 + (((mt * 2 + (quad >> 1)) ^ c7) * 8) + (quad & 1) * 4) = pk;
    }
    asm volatile("s_waitcnt lgkmcnt(0)" ::: "memory");

    // O^T += V^T · P^T
    bf16x8 pb0 = *(const bf16x8*)(PsW + col * 64 + f0);
    bf16x8 pb1 = *(const bf16x8*)(PsW + col * 64 + f1);
#pragma unroll
    for (int dt = 0; dt < 4; dt++) {
      const int rowv = (dt * 16 + col) * 64;
      bf16x8 va0 = *(const bf16x8*)(Vts + rowv + f0);
      bf16x8 va1 = *(const bf16x8*)(Vts + rowv + f1);
      o[dt] = MFMA16(va0, pb0, o[dt]);
      o[dt] = MFMA16(va1, pb1, o[dt]);
    }
  }

  lrow += __shfl_xor(lrow, 16);
  lrow += __shfl_xor(lrow, 32);
  float inv_l = 1.0f / lrow;
  float* op = outp + (size_t)q_tok * ND + h * DHD;
#pragma unroll
  for (int dt = 0; dt < 4; dt++) {
    float4 v;
    v.x = o[dt][0] * inv_l;
    v.y = o[dt][1] * inv_l;
    v.z = o[dt][2] * inv_l;
    v.w = o[dt][3] * inv_l;
    *(float4*)(op + dt * 16 + quad * 4) = v;
  }
}

extern "C" void kernel_launch(void* const* d_in, const int* in_sizes, int n_in,
                              void* d_out, int out_size, void* d_ws, size_t ws_size,
                              hipStream_t stream) {
  const float* X = (const float*)d_in[0];
  unsigned short* ws = (unsigned short*)d_ws;
  unsigned short* Xb = ws + OFF_XB;
  unsigned short* Wb = ws + OFF_WB;
  unsigned short* QK = ws + OFF_QK;
  unsigned short* Vt = ws + OFF_VT;

  // scale = 1/sqrt(Dh) * log2(e), folded into Wq so scores come out in exp2 domain
  const float QSCALE = 0.125f * 1.44269504088896f;

  cvt_kernel<<<3072, 256, 0, stream>>>(X, Xb, 786432, 1.0f);
  wcvt_kernel<<<2880, 256, 0, stream>>>((const float*)d_in[1], (const float*)d_in[2],
                                        (const float*)d_in[3], (const float*)d_in[4],
                                        (const float*)d_in[5], Wb, QSCALE);

  proj_kernel<<<dim3(6, 5, 32), 256, 0, stream>>>(Xb, Wb, QK, Vt);
  attn_kernel<<<dim3(32, 12, 2), 256, 0, stream>>>(QK, Vt, (float*)d_out);
}